// Round 15
// baseline (2675.971 us; speedup 1.0000x reference)
//
#include <hip/hip_runtime.h>
#include <math.h>

#define B_    8
#define N_    96
#define EMB_  768
#define HID_  384
#define GID_  1152   // 3*HID
#define CONC_ 1152   // (L+1)*HID
#define CODE_ 192
#define FEAT_ 768
#define NSL_  64     // slices per batch
#define SD_   6      // dims per slice
#define NRW_  42     // 36 gate rows + 6 M rows (history rows per block)

__device__ __forceinline__ float sigf(float x) { return 1.0f / (1.0f + expf(-x)); }

// LLC-coherent (agent-scope) relaxed atomic accessors (proven visibility path).
__device__ __forceinline__ void atstf(float* p, float v) {
  __hip_atomic_store(p, v, __ATOMIC_RELAXED, __HIP_MEMORY_SCOPE_AGENT);
}
__device__ __forceinline__ float atldf(const float* p) {
  return __hip_atomic_load((float*)p, __ATOMIC_RELAXED, __HIP_MEMORY_SCOPE_AGENT);
}
__device__ __forceinline__ float dot4(float4 a, float4 b) {
  return fmaf(a.x, b.x, fmaf(a.y, b.y, fmaf(a.z, b.z, a.w * b.w)));
}

// ---------------- generic GEMM: C[M,N] = act(A @ W^T + bias) ----------------
template<int RELU>
__global__ __launch_bounds__(256)
void gemm_bias(const float* __restrict__ A, int lda,
               const float* __restrict__ W,
               const float* __restrict__ bias,
               float* __restrict__ C, int ldc, int K)
{
  __shared__ float As[16][68];
  __shared__ float Bs[16][68];
  const int tid = threadIdx.x;
  const int m0 = blockIdx.y * 64;
  const int n0 = blockIdx.x * 64;
  const int lr = tid >> 2;
  const int lc = (tid & 3) * 4;
  const int ty = tid >> 4, tx = tid & 15;
  float acc[4][4] = {};
  for (int k0 = 0; k0 < K; k0 += 16) {
    float4 a4 = *(const float4*)(A + (size_t)(m0 + lr) * lda + k0 + lc);
    float4 b4 = *(const float4*)(W + (size_t)(n0 + lr) * K + k0 + lc);
    As[lc+0][lr] = a4.x; As[lc+1][lr] = a4.y; As[lc+2][lr] = a4.z; As[lc+3][lr] = a4.w;
    Bs[lc+0][lr] = b4.x; Bs[lc+1][lr] = b4.y; Bs[lc+2][lr] = b4.z; Bs[lc+3][lr] = b4.w;
    __syncthreads();
#pragma unroll
    for (int k = 0; k < 16; ++k) {
      float av[4], bv[4];
#pragma unroll
      for (int i = 0; i < 4; ++i) av[i] = As[k][ty*4+i];
#pragma unroll
      for (int j = 0; j < 4; ++j) bv[j] = Bs[k][tx*4+j];
#pragma unroll
      for (int i = 0; i < 4; ++i)
#pragma unroll
        for (int j = 0; j < 4; ++j) acc[i][j] = fmaf(av[i], bv[j], acc[i][j]);
    }
    __syncthreads();
  }
#pragma unroll
  for (int i = 0; i < 4; ++i) {
    int m = m0 + ty*4 + i;
#pragma unroll
    for (int j = 0; j < 4; ++j) {
      int n = n0 + tx*4 + j;
      float v = acc[i][j] + bias[n];
      if (RELU) v = fmaxf(v, 0.0f);
      C[(size_t)m * ldc + n] = v;
    }
  }
}

// ---------- product GEMMs: G[q] = A_q @ W_q, A:[1152,384], W:[384,384] ------
__global__ __launch_bounds__(256)
void prod_kernel(const float* __restrict__ Ac, const float* __restrict__ Ap,
                 const float* __restrict__ W0, const float* __restrict__ W1,
                 float* __restrict__ G)
{
  const float* A = (blockIdx.z < 2) ? Ac : Ap;
  const float* W = (blockIdx.z & 1) ? W1 : W0;
  float* C = G + (size_t)blockIdx.z * GID_ * HID_;
  __shared__ float As[16][68];
  __shared__ float Bs[16][68];
  const int tid = threadIdx.x;
  const int m0 = blockIdx.y * 64;
  const int n0 = blockIdx.x * 64;
  const int lr = tid >> 2;
  const int lc = (tid & 3) * 4;
  const int lr2 = tid & 63, kq = tid >> 6;
  const int ty = tid >> 4, tx = tid & 15;
  float acc[4][4] = {};
  for (int k0 = 0; k0 < HID_; k0 += 16) {
    float4 a4 = *(const float4*)(A + (size_t)(m0 + lr) * HID_ + k0 + lc);
    As[lc+0][lr] = a4.x; As[lc+1][lr] = a4.y; As[lc+2][lr] = a4.z; As[lc+3][lr] = a4.w;
#pragma unroll
    for (int u = 0; u < 4; ++u) {
      int kl = kq * 4 + u;
      Bs[kl][lr2] = W[(size_t)(k0 + kl) * HID_ + n0 + lr2];
    }
    __syncthreads();
#pragma unroll
    for (int k = 0; k < 16; ++k) {
      float av[4], bv[4];
#pragma unroll
      for (int i = 0; i < 4; ++i) av[i] = As[k][ty*4+i];
#pragma unroll
      for (int j = 0; j < 4; ++j) bv[j] = Bs[k][tx*4+j];
#pragma unroll
      for (int i = 0; i < 4; ++i)
#pragma unroll
        for (int j = 0; j < 4; ++j) acc[i][j] = fmaf(av[i], bv[j], acc[i][j]);
    }
    __syncthreads();
  }
#pragma unroll
  for (int i = 0; i < 4; ++i)
#pragma unroll
    for (int j = 0; j < 4; ++j)
      C[(size_t)(m0 + ty*4 + i) * HID_ + n0 + tx*4 + j] = acc[i][j];
}

// ---------------- DAG scan kernel ----------------
// grid = 512 blocks, XCD-aware decode: b=(bid>>3)&7, sl=((bid&7)<<3)|(bid>>6).
// ONE exchange per step. PREWORK (independent of h[i-1]): masked softmax over
// alpha[0..i-2] -> unnormalized E, S_e; history dots -> LDS sdots (no VGPR
// state across the spin). POST: fused load+dot column pass, online-softmax
// rescale, gates, publish. Compiler memory fence after the spin prevents the
// weight loads being hoisted above it (the r10/r14 spill cause).
struct ScanP {
  const float* __restrict__ Hl;
  float*       __restrict__ bufC;
  float*       __restrict__ hnX;     // [8,96,384] exchange (sentinel, atomics)
  const float* __restrict__ G;       // [4][1152,384]
  const float* __restrict__ GIc;
  const float* __restrict__ GHp;
  const float* __restrict__ bhhc;
  const float* __restrict__ bihp;
  const float* __restrict__ Wr0;
  const float* __restrict__ Wr1;
  const float* __restrict__ wk;
  const float* __restrict__ mask;    // enc: adj; dec: adjB (negated use)
  const float* __restrict__ smask;
  float*       __restrict__ adjB;
};

template<int ENC>
__global__ __launch_bounds__(256, 2)
void scan_kernel(ScanP p)
{
  const int tid  = threadIdx.x;
  const int bid  = blockIdx.x;
  const int b    = (bid >> 3) & 7;
  const int sl   = ((bid & 7) << 3) | (bid >> 6);
  const int j0   = sl * SD_;
  const int team = tid >> 4, lane = tid & 15;

  __shared__ __align__(16) float stage[HID_];
  __shared__ float Ew0[N_], Ew1[N_], s_sm[N_], msk[N_];
  __shared__ float alpha[N_];
  __shared__ float dots[48];
  __shared__ float sdots[48];
  __shared__ float red4a[4], red4b[4];
  __shared__ float sh_aknew;
  __shared__ float PA[NRW_ * 97];
  __shared__ float PB[NRW_ * 97];

  // zero history so unguarded sums see 0 beyond written columns
  for (int k = tid; k < NRW_ * 97; k += 256) { PA[k] = 0.f; PB[k] = 0.f; }

  // ---- this thread's 3 weight row-pair pointers (loads stay at use site) ----
  const float4* pA[3];
  const float4* pB[3];
#pragma unroll
  for (int u = 0; u < 3; ++u) {
    const int r = team + 16 * u;
    const float *Aptr, *Bptr;
    if (r < 36) {
      const int g = r / 6, jl = r % 6;
      const size_t off = (size_t)((g % 3) * HID_ + j0 + jl) * HID_;
      const float* base = p.G + (g < 3 ? 0 : 2) * (size_t)GID_ * HID_;
      Aptr = base + off;
      Bptr = base + (size_t)GID_ * HID_ + off;
    } else if (r < 42) {
      const int jl = r - 36;
      Aptr = p.Wr0 + (size_t)(j0 + jl) * HID_;
      Bptr = p.Wr1 + (size_t)(j0 + jl) * HID_;
    } else if (r == 42 && ENC) {
      Aptr = p.wk; Bptr = p.wk;
    } else {
      Aptr = p.Wr0; Bptr = p.Wr1;   // dummy rows, results unused
    }
    pA[u] = (const float4*)Aptr;
    pB[u] = (const float4*)Bptr;
  }

  float bh0=0, bh1=0, bh2=0, bi0=0, bi1=0, bi2=0;
  if (tid < SD_) {
    int j = j0 + tid;
    bh0 = p.bhhc[j]; bh1 = p.bhhc[HID_ + j]; bh2 = p.bhhc[2*HID_ + j];
    bi0 = p.bihp[j]; bi1 = p.bihp[HID_ + j]; bi2 = p.bihp[2*HID_ + j];
  }

#define BULK_STAGE(SRC)                                                      \
  do {                                                                       \
    if (tid < NSL_) {                                                        \
      const float* f_ = (SRC) + tid * SD_;                                   \
      while (__float_as_uint(atldf(f_)) == 0xFFFFFFFFu) {}                   \
    }                                                                        \
    __syncthreads();                                                         \
    {                                                                        \
      float v0 = atldf((SRC) + tid);                                         \
      while (__float_as_uint(v0) == 0xFFFFFFFFu) v0 = atldf((SRC) + tid);    \
      stage[tid] = v0;                                                       \
      if (tid < HID_ - 256) {                                                \
        float v1 = atldf((SRC) + 256 + tid);                                 \
        while (__float_as_uint(v1) == 0xFFFFFFFFu)                           \
          v1 = atldf((SRC) + 256 + tid);                                     \
        stage[256 + tid] = v1;                                               \
      }                                                                      \
    }                                                                        \
    __syncthreads();                                                         \
  } while (0)

  // ---- node 0 ----
  if (tid < SD_) {
    int j = j0 + tid;
    const float* gi = p.GIc + (size_t)(b * N_) * GID_;
    const float* gh = p.GHp + (size_t)(b * N_) * GID_;
    float rc = sigf(gi[j] + bh0);
    float zc = sigf(gi[HID_ + j] + bh1);
    float nc = tanhf(gi[2*HID_ + j] + rc * bh2);
    float outc = (1.0f - zc) * nc;
    float rp = sigf(bi0 + gh[j]);
    float zp = sigf(bi1 + gh[HID_ + j]);
    float np = tanhf(bi2 + rp * gh[2*HID_ + j]);
    float x0 = p.Hl[(size_t)(b * N_) * CONC_ + j];
    float h0 = outc + (1.0f - zp) * np + zp * x0;
    p.bufC[(size_t)(b * N_) * CONC_ + j] = h0;
    atstf(&p.hnX[(size_t)(b * N_) * HID_ + j], h0);
  }
  __syncthreads();

  for (int i = 1; i < N_; ++i) {
    // ================= PREWORK (independent of h[i-1]) =================
    float pf_gi0=0, pf_gi1=0, pf_gi2=0, pf_gh0=0, pf_gh1=0, pf_gh2=0, pf_q=0;
    if (tid < SD_) {
      int j = j0 + tid;
      const float* gi = p.GIc + ((size_t)b * N_ + i) * GID_;
      const float* gh = p.GHp + ((size_t)b * N_ + i) * GID_;
      pf_gi0 = gi[j]; pf_gi1 = gi[HID_ + j]; pf_gi2 = gi[2*HID_ + j];
      pf_gh0 = gh[j]; pf_gh1 = gh[HID_ + j]; pf_gh2 = gh[2*HID_ + j];
      pf_q   = p.Hl[((size_t)b * N_ + i) * CONC_ + j];
    }
    float mr = 0.f, sv_ = 0.f;
    if (tid < N_) {
      mr  = p.mask[((size_t)b * N_ + i) * N_ + tid];
      sv_ = p.smask[((size_t)b * N_ + i) * N_ + tid];
      msk[tid] = mr; s_sm[tid] = sv_;
    }
    float f_mx = 0.f, f_se = 0.f;
    if (ENC) {
      // masked logits over n < i-1 (alpha[i-1] arrives later this step)
      float av = -3.0e38f;
      if (tid < i - 1) av = alpha[tid] - (1.0f - mr) * 1e30f;
      float v = av;
#pragma unroll
      for (int m = 32; m; m >>= 1) v = fmaxf(v, __shfl_xor(v, m));
      if ((tid & 63) == 0) red4a[tid >> 6] = v;
      __syncthreads();
      f_mx = fmaxf(fmaxf(red4a[0], red4a[1]), fmaxf(red4a[2], red4a[3]));
      float e = (tid < i - 1) ? expf(av - f_mx) : 0.0f;
      v = e;
#pragma unroll
      for (int m = 32; m; m >>= 1) v += __shfl_xor(v, m);
      if ((tid & 63) == 0) red4b[tid >> 6] = v;
      if (tid < N_) { Ew0[tid] = e * sv_; Ew1[tid] = e - e * sv_; }
      __syncthreads();
      f_se = red4b[0] + red4b[1] + red4b[2] + red4b[3];
    } else {
      if (tid < N_) {
        float w = (tid < i - 1) ? -mr : 0.0f;
        Ew0[tid] = w * sv_; Ew1[tid] = w - w * sv_;
      }
      __syncthreads();
    }

    // history dots over n<=i-2 -> LDS sdots (no register state across spin)
    {
      float er0[6], er1[6];
#pragma unroll
      for (int k = 0; k < 6; ++k) {
        er0[k] = Ew0[lane + 16*k];
        er1[k] = Ew1[lane + 16*k];
      }
#pragma unroll
      for (int u = 0; u < 3; ++u) {
        const int r = team + 16 * u;
        if (r < NRW_) {
          float acc = 0.f;
#pragma unroll
          for (int k = 0; k < 6; ++k) {
            int n = lane + 16*k;
            acc = fmaf(er0[k], PA[r * 97 + n], fmaf(er1[k], PB[r * 97 + n], acc));
          }
#pragma unroll
          for (int mm = 8; mm; mm >>= 1) acc += __shfl_xor(acc, mm);
          if (lane == 0) sdots[r] = acc;
        }
      }
    }

    // ================= WAIT: stage hn[i-1] =================
    const float* srcH = p.hnX + (size_t)(b * N_ + (i - 1)) * HID_;
    BULK_STAGE(srcH);
    asm volatile("" ::: "memory");   // forbid hoisting post-loads above spin
    const float4* st4 = (const float4*)stage;
    float4 hreg[6];
#pragma unroll
    for (int m = 0; m < 6; ++m) hreg[m] = st4[lane + 16*m];

    // ================= POST: fused load+dot column pass =================
    float a_keep[3], b_keep[3];
#pragma unroll
    for (int u = 0; u < 3; ++u) {
      float a = 0.f, bv = 0.f;
#pragma unroll
      for (int m = 0; m < 6; ++m) {
        float4 wa = pA[u][lane + 16*m];
        float4 wb = pB[u][lane + 16*m];
        a  += dot4(wa, hreg[m]);
        bv += dot4(wb, hreg[m]);
      }
#pragma unroll
      for (int mm = 8; mm; mm >>= 1) {
        a  += __shfl_xor(a, mm);
        bv += __shfl_xor(bv, mm);
      }
      a_keep[u] = a; b_keep[u] = bv;
      const int r = team + 16 * u;
      if (lane == 0) {
        if (r < NRW_) { PA[r * 97 + (i - 1)] = a; PB[r * 97 + (i - 1)] = bv; }
        else if (ENC && r == 42) sh_aknew = a;
      }
    }
    __syncthreads();

    float c_scale, c_elast, c_inv;
    if (ENC) {
      float av_last = sh_aknew - (1.0f - msk[i - 1]) * 1e30f;
      float m_new = fmaxf(f_mx, av_last);
      c_scale = expf(f_mx - m_new);
      c_elast = expf(av_last - m_new);
      c_inv = 1.0f / (f_se * c_scale + c_elast);
    } else {
      c_scale = 1.0f; c_elast = -msk[i - 1]; c_inv = 1.0f;
    }
    float s_last = s_sm[i - 1];
#pragma unroll
    for (int u = 0; u < 3; ++u) {
      const int r = team + 16 * u;
      if (r < NRW_ && lane == 0)
        dots[r] = (sdots[r] * c_scale
                   + c_elast * (s_last * a_keep[u] + (1.0f - s_last) * b_keep[u]))
                  * c_inv;
    }
    if (ENC && tid == 0) alpha[i - 1] = sh_aknew;
    __syncthreads();

    // ---- combine gates, publish hn ----
    if (tid < SD_) {
      int j = j0 + tid;
      float Mj = dots[36 + tid];
      float rc = sigf(pf_gi0 + dots[tid] + bh0);
      float zc = sigf(pf_gi1 + dots[6 + tid] + bh1);
      float nc = tanhf(pf_gi2 + rc * (dots[12 + tid] + bh2));
      float outc = (1.0f - zc) * nc + zc * Mj;
      float rp = sigf(dots[18 + tid] + bi0 + pf_gh0);
      float zp = sigf(dots[24 + tid] + bi1 + pf_gh1);
      float np = tanhf(dots[30 + tid] + bi2 + rp * pf_gh2);
      float hv = outc + (1.0f - zp) * np + zp * pf_q;
      p.bufC[((size_t)b * N_ + i) * CONC_ + j] = hv;
      atstf(&p.hnX[((size_t)b * N_ + i) * HID_ + j], hv);
    }
    if (ENC && sl == 0 && tid < N_) {
      float w;
      if (tid < i - 1)       w = (Ew0[tid] + Ew1[tid]) * c_scale * c_inv;
      else if (tid == i - 1) w = c_elast * c_inv;
      else                   w = 0.0f;
      p.adjB[((size_t)b * N_ + i) * N_ + tid] = w;
    }
    __syncthreads();   // protect stage/dots/Ew/msk/alpha before next iter
  }
#undef BULK_STAGE
}

// ---------------- feature_map = I - adjB2 (row 0 implicit 0) ----------------
__global__ __launch_bounds__(256)
void fmap_kernel(const float* __restrict__ adjB2, float* __restrict__ out)
{
  int idx = blockIdx.x * 256 + threadIdx.x;
  if (idx < B_ * N_ * N_) {
    int j = idx % N_;
    int i = (idx / N_) % N_;
    float a = (i == 0) ? 0.0f : adjB2[idx];
    out[idx] = ((i == j) ? 1.0f : 0.0f) - a;
  }
}

// ---------------- orchestration ----------------
extern "C" void kernel_launch(void* const* d_in, const int* in_sizes, int n_in,
                              void* d_out, int out_size, void* d_ws, size_t ws_size,
                              hipStream_t stream)
{
  (void)in_sizes; (void)n_in; (void)out_size; (void)ws_size;
  const float* features     = (const float*)d_in[0];
  const float* adj          = (const float*)d_in[1];
  const float* s_mask       = (const float*)d_in[2];
  const float* enc_fc1_W    = (const float*)d_in[5];
  const float* enc_fc1_b    = (const float*)d_in[6];
  const float* enc_gat_w    = (const float*)d_in[7];
  const float* enc_Wr0      = (const float*)d_in[9];
  const float* enc_Wr1      = (const float*)d_in[10];
  const float* enc_gruc_Wih = (const float*)d_in[11];
  const float* enc_gruc_Whh = (const float*)d_in[12];
  const float* enc_gruc_bih = (const float*)d_in[13];
  const float* enc_gruc_bhh = (const float*)d_in[14];
  const float* enc_grup_Wih = (const float*)d_in[15];
  const float* enc_grup_Whh = (const float*)d_in[16];
  const float* enc_grup_bih = (const float*)d_in[17];
  const float* enc_grup_bhh = (const float*)d_in[18];
  const float* enc_mlp_W0   = (const float*)d_in[19];
  const float* enc_mlp_b0   = (const float*)d_in[20];
  const float* enc_mlp_W1   = (const float*)d_in[21];
  const float* enc_mlp_b1   = (const float*)d_in[22];
  const float* dec_fc1_W    = (const float*)d_in[23];
  const float* dec_fc1_b    = (const float*)d_in[24];
  const float* dec_Wr0      = (const float*)d_in[25];
  const float* dec_Wr1      = (const float*)d_in[26];
  const float* dec_gruc_Wih = (const float*)d_in[27];
  const float* dec_gruc_Whh = (const float*)d_in[28];
  const float* dec_gruc_bih = (const float*)d_in[29];
  const float* dec_gruc_bhh = (const float*)d_in[30];
  const float* dec_grup_Wih = (const float*)d_in[31];
  const float* dec_grup_Whh = (const float*)d_in[32];
  const float* dec_grup_bih = (const float*)d_in[33];
  const float* dec_grup_bhh = (const float*)d_in[34];
  const float* dec_mlp_W0   = (const float*)d_in[35];
  const float* dec_mlp_b0   = (const float*)d_in[36];
  const float* dec_mlp_W1   = (const float*)d_in[37];
  const float* dec_mlp_b1   = (const float*)d_in[38];

  float* ws = (float*)d_ws;
  size_t o = 0;
  float* Hse   = ws + o; o += (size_t)B_ * N_ * CONC_;
  float* Hsd   = ws + o; o += (size_t)B_ * N_ * CONC_;
  float* GIc   = ws + o; o += (size_t)B_ * N_ * GID_;
  float* GHp   = ws + o; o += (size_t)B_ * N_ * GID_;
  float* adjB1 = ws + o; o += (size_t)B_ * N_ * N_;
  float* adjB2 = ws + o; o += (size_t)B_ * N_ * N_;
  float* fU    = ws + o; o += (size_t)B_ * N_ * CODE_;
  float* Tmp   = ws + o; o += (size_t)B_ * N_ * HID_;
  float* hnX   = ws + o; o += (size_t)B_ * N_ * HID_;
  float* Gbuf  = ws + o; o += (size_t)4 * GID_ * HID_;
  const size_t hn_bytes = (size_t)B_ * N_ * HID_ * sizeof(float);

  const dim3 blk(256);
  float* logits = (float*)d_out;
  float* fmap   = (float*)d_out + (size_t)B_ * N_ * FEAT_;

  // encoder fc1
  gemm_bias<1><<<dim3(6, 12), blk, 0, stream>>>(features, EMB_, enc_fc1_W, enc_fc1_b,
                                                Hse, CONC_, EMB_);
  // encoder scans
  for (int l = 0; l < 2; ++l) {
    const float* Hl = Hse + l * HID_;
    gemm_bias<0><<<dim3(18, 12), blk, 0, stream>>>(Hl, CONC_,
        enc_gruc_Wih + (size_t)l * GID_ * HID_, enc_gruc_bih + l * GID_, GIc, GID_, HID_);
    gemm_bias<0><<<dim3(18, 12), blk, 0, stream>>>(Hl, CONC_,
        enc_grup_Whh + (size_t)l * GID_ * HID_, enc_grup_bhh + l * GID_, GHp, GID_, HID_);
    prod_kernel<<<dim3(6, 18, 4), blk, 0, stream>>>(
        enc_gruc_Whh + (size_t)l * GID_ * HID_, enc_grup_Wih + (size_t)l * GID_ * HID_,
        enc_Wr0 + (size_t)l * HID_ * HID_, enc_Wr1 + (size_t)l * HID_ * HID_, Gbuf);
    hipMemsetAsync(hnX, 0xFF, hn_bytes, stream);
    ScanP p;
    p.Hl = Hl; p.bufC = Hse + (l + 1) * HID_;
    p.hnX = hnX; p.G = Gbuf;
    p.GIc = GIc; p.GHp = GHp;
    p.bhhc = enc_gruc_bhh + l * GID_;
    p.bihp = enc_grup_bih + l * GID_;
    p.Wr0 = enc_Wr0 + (size_t)l * HID_ * HID_;
    p.Wr1 = enc_Wr1 + (size_t)l * HID_ * HID_;
    p.wk = enc_gat_w + l * 2 * HID_ + HID_;
    p.mask = adj; p.smask = s_mask;
    p.adjB = (l == 0) ? adjB1 : adjB2;
    scan_kernel<1><<<dim3(512), blk, 0, stream>>>(p);
  }
  // encoder MLP -> fU
  gemm_bias<1><<<dim3(6, 12), blk, 0, stream>>>(Hse, CONC_, enc_mlp_W0, enc_mlp_b0,
                                                Tmp, HID_, CONC_);
  gemm_bias<0><<<dim3(3, 12), blk, 0, stream>>>(Tmp, HID_, enc_mlp_W1, enc_mlp_b1,
                                                fU, CODE_, HID_);
  // decoder fc1
  gemm_bias<1><<<dim3(6, 12), blk, 0, stream>>>(fU, CODE_, dec_fc1_W, dec_fc1_b,
                                                Hsd, CONC_, CODE_);
  // decoder scans
  for (int l = 0; l < 2; ++l) {
    const float* Hl = Hsd + l * HID_;
    gemm_bias<0><<<dim3(18, 12), blk, 0, stream>>>(Hl, CONC_,
        dec_gruc_Wih + (size_t)l * GID_ * HID_, dec_gruc_bih + l * GID_, GIc, GID_, HID_);
    gemm_bias<0><<<dim3(18, 12), blk, 0, stream>>>(Hl, CONC_,
        dec_grup_Whh + (size_t)l * GID_ * HID_, dec_grup_bhh + l * GID_, GHp, GID_, HID_);
    prod_kernel<<<dim3(6, 18, 4), blk, 0, stream>>>(
        dec_gruc_Whh + (size_t)l * GID_ * HID_, dec_grup_Wih + (size_t)l * GID_ * HID_,
        dec_Wr0 + (size_t)l * HID_ * HID_, dec_Wr1 + (size_t)l * HID_ * HID_, Gbuf);
    hipMemsetAsync(hnX, 0xFF, hn_bytes, stream);
    ScanP p;
    p.Hl = Hl; p.bufC = Hsd + (l + 1) * HID_;
    p.hnX = hnX; p.G = Gbuf;
    p.GIc = GIc; p.GHp = GHp;
    p.bhhc = dec_gruc_bhh + l * GID_;
    p.bihp = dec_grup_bih + l * GID_;
    p.Wr0 = dec_Wr0 + (size_t)l * HID_ * HID_;
    p.Wr1 = dec_Wr1 + (size_t)l * HID_ * HID_;
    p.wk = nullptr;
    p.mask = (l == 0) ? adjB1 : adjB2;   // w[n] = -adjB[b,i,n] for n<i
    p.smask = s_mask;
    p.adjB = nullptr;
    scan_kernel<0><<<dim3(512), blk, 0, stream>>>(p);
  }
  // decoder MLP -> logits
  gemm_bias<1><<<dim3(6, 12), blk, 0, stream>>>(Hsd, CONC_, dec_mlp_W0, dec_mlp_b0,
                                                Tmp, HID_, CONC_);
  gemm_bias<0><<<dim3(12, 12), blk, 0, stream>>>(Tmp, HID_, dec_mlp_W1, dec_mlp_b1,
                                                 logits, FEAT_, HID_);
  // feature_map
  fmap_kernel<<<dim3((B_ * N_ * N_ + 255) / 256), blk, 0, stream>>>(adjB2, fmap);
}

// Round 16
// 1959.344 us; speedup vs baseline: 1.3657x; 1.3657x over previous
//
#include <hip/hip_runtime.h>
#include <math.h>

#define B_    8
#define N_    96
#define EMB_  768
#define HID_  384
#define GID_  1152   // 3*HID
#define CONC_ 1152   // (L+1)*HID
#define CODE_ 192
#define FEAT_ 768
#define NSL_  64     // slices per batch
#define SD_   6      // dims per slice
#define NRW_  42     // 36 gate rows + 6 M rows (history rows per block)

__device__ __forceinline__ float sigf(float x) { return 1.0f / (1.0f + expf(-x)); }

// LLC-coherent (agent-scope) relaxed atomic accessors (proven visibility path).
__device__ __forceinline__ void atstf(float* p, float v) {
  __hip_atomic_store(p, v, __ATOMIC_RELAXED, __HIP_MEMORY_SCOPE_AGENT);
}
__device__ __forceinline__ float atldf(const float* p) {
  return __hip_atomic_load((float*)p, __ATOMIC_RELAXED, __HIP_MEMORY_SCOPE_AGENT);
}
__device__ __forceinline__ float dot4(float4 a, float4 b) {
  return fmaf(a.x, b.x, fmaf(a.y, b.y, fmaf(a.z, b.z, a.w * b.w)));
}

// ---------------- generic GEMM: C[M,N] = act(A @ W^T + bias) ----------------
template<int RELU>
__global__ __launch_bounds__(256)
void gemm_bias(const float* __restrict__ A, int lda,
               const float* __restrict__ W,
               const float* __restrict__ bias,
               float* __restrict__ C, int ldc, int K)
{
  __shared__ float As[16][68];
  __shared__ float Bs[16][68];
  const int tid = threadIdx.x;
  const int m0 = blockIdx.y * 64;
  const int n0 = blockIdx.x * 64;
  const int lr = tid >> 2;
  const int lc = (tid & 3) * 4;
  const int ty = tid >> 4, tx = tid & 15;
  float acc[4][4] = {};
  for (int k0 = 0; k0 < K; k0 += 16) {
    float4 a4 = *(const float4*)(A + (size_t)(m0 + lr) * lda + k0 + lc);
    float4 b4 = *(const float4*)(W + (size_t)(n0 + lr) * K + k0 + lc);
    As[lc+0][lr] = a4.x; As[lc+1][lr] = a4.y; As[lc+2][lr] = a4.z; As[lc+3][lr] = a4.w;
    Bs[lc+0][lr] = b4.x; Bs[lc+1][lr] = b4.y; Bs[lc+2][lr] = b4.z; Bs[lc+3][lr] = b4.w;
    __syncthreads();
#pragma unroll
    for (int k = 0; k < 16; ++k) {
      float av[4], bv[4];
#pragma unroll
      for (int i = 0; i < 4; ++i) av[i] = As[k][ty*4+i];
#pragma unroll
      for (int j = 0; j < 4; ++j) bv[j] = Bs[k][tx*4+j];
#pragma unroll
      for (int i = 0; i < 4; ++i)
#pragma unroll
        for (int j = 0; j < 4; ++j) acc[i][j] = fmaf(av[i], bv[j], acc[i][j]);
    }
    __syncthreads();
  }
#pragma unroll
  for (int i = 0; i < 4; ++i) {
    int m = m0 + ty*4 + i;
#pragma unroll
    for (int j = 0; j < 4; ++j) {
      int n = n0 + tx*4 + j;
      float v = acc[i][j] + bias[n];
      if (RELU) v = fmaxf(v, 0.0f);
      C[(size_t)m * ldc + n] = v;
    }
  }
}

// ---------- product GEMMs: G[q] = A_q @ W_q, A:[1152,384], W:[384,384] ------
// q = blockIdx.z: 0:Whhc@Wr0 1:Whhc@Wr1 2:Wihp@Wr0 3:Wihp@Wr1
__global__ __launch_bounds__(256)
void prod_kernel(const float* __restrict__ Ac, const float* __restrict__ Ap,
                 const float* __restrict__ W0, const float* __restrict__ W1,
                 float* __restrict__ G)
{
  const float* A = (blockIdx.z < 2) ? Ac : Ap;
  const float* W = (blockIdx.z & 1) ? W1 : W0;
  float* C = G + (size_t)blockIdx.z * GID_ * HID_;
  __shared__ float As[16][68];
  __shared__ float Bs[16][68];
  const int tid = threadIdx.x;
  const int m0 = blockIdx.y * 64;
  const int n0 = blockIdx.x * 64;
  const int lr = tid >> 2;
  const int lc = (tid & 3) * 4;
  const int lr2 = tid & 63, kq = tid >> 6;
  const int ty = tid >> 4, tx = tid & 15;
  float acc[4][4] = {};
  for (int k0 = 0; k0 < HID_; k0 += 16) {
    float4 a4 = *(const float4*)(A + (size_t)(m0 + lr) * HID_ + k0 + lc);
    As[lc+0][lr] = a4.x; As[lc+1][lr] = a4.y; As[lc+2][lr] = a4.z; As[lc+3][lr] = a4.w;
#pragma unroll
    for (int u = 0; u < 4; ++u) {
      int kl = kq * 4 + u;
      Bs[kl][lr2] = W[(size_t)(k0 + kl) * HID_ + n0 + lr2];
    }
    __syncthreads();
#pragma unroll
    for (int k = 0; k < 16; ++k) {
      float av[4], bv[4];
#pragma unroll
      for (int i = 0; i < 4; ++i) av[i] = As[k][ty*4+i];
#pragma unroll
      for (int j = 0; j < 4; ++j) bv[j] = Bs[k][tx*4+j];
#pragma unroll
      for (int i = 0; i < 4; ++i)
#pragma unroll
        for (int j = 0; j < 4; ++j) acc[i][j] = fmaf(av[i], bv[j], acc[i][j]);
    }
    __syncthreads();
  }
#pragma unroll
  for (int i = 0; i < 4; ++i)
#pragma unroll
    for (int j = 0; j < 4; ++j)
      C[(size_t)(m0 + ty*4 + i) * HID_ + n0 + tx*4 + j] = acc[i][j];
}

// ---------------- DAG scan kernel ----------------
// grid = 512 blocks: batch = blockIdx>>6, slice = blockIdx&63 (6 dims each).
// ONE exchange per step (hn all-gather); gates+M via G-product rows and
// incremental per-block history PA/PB.
struct ScanP {
  const float* Hl;      // q rows, stride CONC_
  float*       bufC;    // cached output rows, stride CONC_
  float*       hnX;     // [8,96,384] exchange (sentinel-filled, atomics)
  const float* G;       // [4][1152,384] products for this scan
  const float* GIc;     // [768,1152] q@Wih_c^T + bih_c
  const float* GHp;     // [768,1152] q@Whh_p^T + bhh_p
  const float* bhhc;    // [1152]
  const float* bihp;    // [1152]
  const float* Wr0;     // [384,384]
  const float* Wr1;     // [384,384]
  const float* wk;      // [384] (enc only)
  const float* mask;    // enc: adj; dec: adjB (negated use)
  const float* smask;   // [8,96,96]
  float*       adjB;    // enc output
};

template<int ENC>
__global__ __launch_bounds__(256, 2)
void scan_kernel(ScanP p)
{
  const int tid  = threadIdx.x;
  const int b    = blockIdx.x >> 6;
  const int sl   = blockIdx.x & 63;
  const int j0   = sl * SD_;
  const int team = tid >> 4, lane = tid & 15;

  __shared__ __align__(16) float stage[HID_];
  __shared__ float ws0[N_], ws1[N_], s_sm[N_];
  __shared__ float alpha[N_];
  __shared__ float dots[48];
  __shared__ float red4[4];
  __shared__ float sh_aknew;
  __shared__ float PA[NRW_ * 97];
  __shared__ float PB[NRW_ * 97];

  // zero history so the unguarded dot loop multiplies 0*0 beyond column i-1
  for (int k = tid; k < NRW_ * 97; k += 256) { PA[k] = 0.f; PB[k] = 0.f; }

  // ---- hoist the block's 48 virtual row-pairs into registers ----
  // r = team + 16u: r<36 gate rows (g=r/6: 0..2 c-side r/z/n, 3..5 p-side),
  // r in 36..41: M rows (Wr0/Wr1); r==42: wk (enc); r>42: dummy.
  // All loads UNCONDITIONAL so the compiler can promote to registers.
  float4 wAr[3][6], wBr[3][6];
#pragma unroll
  for (int u = 0; u < 3; ++u) {
    const int r = team + 16 * u;
    const float *Aptr, *Bptr;
    if (r < 36) {
      const int g = r / 6, jl = r % 6;
      const size_t off = (size_t)((g % 3) * HID_ + j0 + jl) * HID_;
      const float* base = p.G + (g < 3 ? 0 : 2) * (size_t)GID_ * HID_;
      Aptr = base + off;
      Bptr = base + (size_t)GID_ * HID_ + off;
    } else if (r < 42) {
      const int jl = r - 36;
      Aptr = p.Wr0 + (size_t)(j0 + jl) * HID_;
      Bptr = p.Wr1 + (size_t)(j0 + jl) * HID_;
    } else if (r == 42 && ENC) {
      Aptr = p.wk; Bptr = p.wk;
    } else {
      Aptr = p.Wr0; Bptr = p.Wr1;   // dummy rows, results unused
    }
#pragma unroll
    for (int m = 0; m < 6; ++m) {
      wAr[u][m] = ((const float4*)Aptr)[lane + 16*m];
      wBr[u][m] = ((const float4*)Bptr)[lane + 16*m];
    }
  }
  float bh0=0, bh1=0, bh2=0, bi0=0, bi1=0, bi2=0;
  if (tid < SD_) {
    int j = j0 + tid;
    bh0 = p.bhhc[j]; bh1 = p.bhhc[HID_ + j]; bh2 = p.bhhc[2*HID_ + j];
    bi0 = p.bihp[j]; bi1 = p.bihp[HID_ + j]; bi2 = p.bihp[2*HID_ + j];
  }

#define BULK_STAGE(SRC)                                                      \
  do {                                                                       \
    if (tid < NSL_) {                                                        \
      const float* f_ = (SRC) + tid * SD_;                                   \
      while (__float_as_uint(atldf(f_)) == 0xFFFFFFFFu) {}                   \
    }                                                                        \
    __syncthreads();                                                         \
    {                                                                        \
      float v0 = atldf((SRC) + tid);                                         \
      while (__float_as_uint(v0) == 0xFFFFFFFFu) v0 = atldf((SRC) + tid);    \
      stage[tid] = v0;                                                       \
      if (tid < HID_ - 256) {                                                \
        float v1 = atldf((SRC) + 256 + tid);                                 \
        while (__float_as_uint(v1) == 0xFFFFFFFFu)                           \
          v1 = atldf((SRC) + 256 + tid);                                     \
        stage[256 + tid] = v1;                                               \
      }                                                                      \
    }                                                                        \
    __syncthreads();                                                         \
  } while (0)

  // ---- node 0 ----
  if (tid < SD_) {
    int j = j0 + tid;
    const float* gi = p.GIc + (size_t)(b * N_) * GID_;
    const float* gh = p.GHp + (size_t)(b * N_) * GID_;
    float rc = sigf(gi[j] + bh0);
    float zc = sigf(gi[HID_ + j] + bh1);
    float nc = tanhf(gi[2*HID_ + j] + rc * bh2);
    float outc = (1.0f - zc) * nc;
    float rp = sigf(bi0 + gh[j]);
    float zp = sigf(bi1 + gh[HID_ + j]);
    float np = tanhf(bi2 + rp * gh[2*HID_ + j]);
    float x0 = p.Hl[(size_t)(b * N_) * CONC_ + j];
    float h0 = outc + (1.0f - zp) * np + zp * x0;
    p.bufC[(size_t)(b * N_) * CONC_ + j] = h0;
    atstf(&p.hnX[(size_t)(b * N_) * HID_ + j], h0);
  }
  __syncthreads();

  for (int i = 1; i < N_; ++i) {
    // ---- prefetch step-i operands (hide under hn flight) ----
    float pf_gi0=0, pf_gi1=0, pf_gi2=0, pf_gh0=0, pf_gh1=0, pf_gh2=0, pf_q=0;
    if (tid < SD_) {
      int j = j0 + tid;
      const float* gi = p.GIc + ((size_t)b * N_ + i) * GID_;
      const float* gh = p.GHp + ((size_t)b * N_ + i) * GID_;
      pf_gi0 = gi[j]; pf_gi1 = gi[HID_ + j]; pf_gi2 = gi[2*HID_ + j];
      pf_gh0 = gh[j]; pf_gh1 = gh[HID_ + j]; pf_gh2 = gh[2*HID_ + j];
      pf_q   = p.Hl[((size_t)b * N_ + i) * CONC_ + j];
    }
    float pf_mrow = 0.0f;
    if (tid < N_) {
      pf_mrow = p.mask[((size_t)b * N_ + i) * N_ + tid];
      s_sm[tid] = p.smask[((size_t)b * N_ + i) * N_ + tid];
    }

    // ---- ONE exchange: wait + stage hn[i-1] ----
    const float* srcH = p.hnX + (size_t)(b * N_ + (i - 1)) * HID_;
    BULK_STAGE(srcH);
    const float4* st4 = (const float4*)stage;
    float4 hreg[6];
#pragma unroll
    for (int m = 0; m < 6; ++m) hreg[m] = st4[lane + 16*m];

    // ---- append history column: PA/PB[r][i-1] = A_r@h, B_r@h ----
#pragma unroll
    for (int u = 0; u < 3; ++u) {
      const int r = team + 16 * u;
      float a = 0.f, bv = 0.f;
#pragma unroll
      for (int m = 0; m < 6; ++m) {
        a  += dot4(wAr[u][m], hreg[m]);
        bv += dot4(wBr[u][m], hreg[m]);
      }
#pragma unroll
      for (int mm = 8; mm; mm >>= 1) {
        a  += __shfl_xor(a, mm);
        bv += __shfl_xor(bv, mm);
      }
      if (lane == 0) {
        if (r < NRW_) { PA[r * 97 + (i - 1)] = a; PB[r * 97 + (i - 1)] = bv; }
        else if (ENC && r == 42) sh_aknew = a;
      }
    }
    __syncthreads();

    // ---- attention weights, pre-scaled by s ----
    if (ENC) {
      if (tid == 0) alpha[i - 1] = sh_aknew;
      float av = -3.0e38f;
      if (tid < i) {
        float ak = (tid == i - 1) ? sh_aknew : alpha[tid];
        av = ak - (1.0f - pf_mrow) * 1e30f;
      }
      float v = av;
#pragma unroll
      for (int m = 32; m; m >>= 1) v = fmaxf(v, __shfl_xor(v, m));
      if ((tid & 63) == 0) red4[tid >> 6] = v;
      __syncthreads();
      float mx = fmaxf(fmaxf(red4[0], red4[1]), fmaxf(red4[2], red4[3]));
      __syncthreads();
      float e = (tid < i) ? expf(av - mx) : 0.0f;
      v = e;
#pragma unroll
      for (int m = 32; m; m >>= 1) v += __shfl_xor(v, m);
      if ((tid & 63) == 0) red4[tid >> 6] = v;
      __syncthreads();
      float ssum = red4[0] + red4[1] + red4[2] + red4[3];
      if (tid < N_) {
        float w = (tid < i) ? e / ssum : 0.0f;
        float sv = s_sm[tid];
        ws0[tid] = w * sv;
        ws1[tid] = w - w * sv;
        if (sl == 0) p.adjB[((size_t)b * N_ + i) * N_ + tid] = w;
      }
      __syncthreads();
    } else {
      if (tid < N_) {
        float w = (tid < i) ? -pf_mrow : 0.0f;
        float sv = s_sm[tid];
        ws0[tid] = w * sv;
        ws1[tid] = w - w * sv;
      }
      __syncthreads();
    }

    // ---- dots[r] = sum_n ws0[n]*PA[r][n] + ws1[n]*PB[r][n] ----
    {
      float wsr0[6], wsr1[6];
#pragma unroll
      for (int k = 0; k < 6; ++k) {
        wsr0[k] = ws0[lane + 16*k];
        wsr1[k] = ws1[lane + 16*k];
      }
#pragma unroll
      for (int u = 0; u < 3; ++u) {
        const int r = team + 16 * u;
        if (r < NRW_) {
          float acc = 0.f;
#pragma unroll
          for (int k = 0; k < 6; ++k) {
            int n = lane + 16*k;
            acc = fmaf(wsr0[k], PA[r * 97 + n], fmaf(wsr1[k], PB[r * 97 + n], acc));
          }
#pragma unroll
          for (int mm = 8; mm; mm >>= 1) acc += __shfl_xor(acc, mm);
          if (lane == 0) dots[r] = acc;
        }
      }
    }
    __syncthreads();

    // ---- combine gates, publish hn ----
    if (tid < SD_) {
      int j = j0 + tid;
      float Mj = dots[36 + tid];
      float rc = sigf(pf_gi0 + dots[tid] + bh0);
      float zc = sigf(pf_gi1 + dots[6 + tid] + bh1);
      float nc = tanhf(pf_gi2 + rc * (dots[12 + tid] + bh2));
      float outc = (1.0f - zc) * nc + zc * Mj;
      float rp = sigf(dots[18 + tid] + bi0 + pf_gh0);
      float zp = sigf(dots[24 + tid] + bi1 + pf_gh1);
      float np = tanhf(dots[30 + tid] + bi2 + rp * pf_gh2);
      float hv = outc + (1.0f - zp) * np + zp * pf_q;
      p.bufC[((size_t)b * N_ + i) * CONC_ + j] = hv;
      atstf(&p.hnX[((size_t)b * N_ + i) * HID_ + j], hv);
    }
    __syncthreads();   // protect stage[]/dots before next iteration
  }
#undef BULK_STAGE
}

// ---------------- feature_map = I - adjB2 (row 0 implicit 0) ----------------
__global__ __launch_bounds__(256)
void fmap_kernel(const float* __restrict__ adjB2, float* __restrict__ out)
{
  int idx = blockIdx.x * 256 + threadIdx.x;
  if (idx < B_ * N_ * N_) {
    int j = idx % N_;
    int i = (idx / N_) % N_;
    float a = (i == 0) ? 0.0f : adjB2[idx];
    out[idx] = ((i == j) ? 1.0f : 0.0f) - a;
  }
}

// ---------------- orchestration ----------------
extern "C" void kernel_launch(void* const* d_in, const int* in_sizes, int n_in,
                              void* d_out, int out_size, void* d_ws, size_t ws_size,
                              hipStream_t stream)
{
  (void)in_sizes; (void)n_in; (void)out_size; (void)ws_size;
  const float* features     = (const float*)d_in[0];
  const float* adj          = (const float*)d_in[1];
  const float* s_mask       = (const float*)d_in[2];
  const float* enc_fc1_W    = (const float*)d_in[5];
  const float* enc_fc1_b    = (const float*)d_in[6];
  const float* enc_gat_w    = (const float*)d_in[7];
  const float* enc_Wr0      = (const float*)d_in[9];
  const float* enc_Wr1      = (const float*)d_in[10];
  const float* enc_gruc_Wih = (const float*)d_in[11];
  const float* enc_gruc_Whh = (const float*)d_in[12];
  const float* enc_gruc_bih = (const float*)d_in[13];
  const float* enc_gruc_bhh = (const float*)d_in[14];
  const float* enc_grup_Wih = (const float*)d_in[15];
  const float* enc_grup_Whh = (const float*)d_in[16];
  const float* enc_grup_bih = (const float*)d_in[17];
  const float* enc_grup_bhh = (const float*)d_in[18];
  const float* enc_mlp_W0   = (const float*)d_in[19];
  const float* enc_mlp_b0   = (const float*)d_in[20];
  const float* enc_mlp_W1   = (const float*)d_in[21];
  const float* enc_mlp_b1   = (const float*)d_in[22];
  const float* dec_fc1_W    = (const float*)d_in[23];
  const float* dec_fc1_b    = (const float*)d_in[24];
  const float* dec_Wr0      = (const float*)d_in[25];
  const float* dec_Wr1      = (const float*)d_in[26];
  const float* dec_gruc_Wih = (const float*)d_in[27];
  const float* dec_gruc_Whh = (const float*)d_in[28];
  const float* dec_gruc_bih = (const float*)d_in[29];
  const float* dec_gruc_bhh = (const float*)d_in[30];
  const float* dec_grup_Wih = (const float*)d_in[31];
  const float* dec_grup_Whh = (const float*)d_in[32];
  const float* dec_grup_bih = (const float*)d_in[33];
  const float* dec_grup_bhh = (const float*)d_in[34];
  const float* dec_mlp_W0   = (const float*)d_in[35];
  const float* dec_mlp_b0   = (const float*)d_in[36];
  const float* dec_mlp_W1   = (const float*)d_in[37];
  const float* dec_mlp_b1   = (const float*)d_in[38];

  float* ws = (float*)d_ws;
  size_t o = 0;
  float* Hse   = ws + o; o += (size_t)B_ * N_ * CONC_;
  float* Hsd   = ws + o; o += (size_t)B_ * N_ * CONC_;
  float* GIc   = ws + o; o += (size_t)B_ * N_ * GID_;
  float* GHp   = ws + o; o += (size_t)B_ * N_ * GID_;
  float* adjB1 = ws + o; o += (size_t)B_ * N_ * N_;
  float* adjB2 = ws + o; o += (size_t)B_ * N_ * N_;
  float* fU    = ws + o; o += (size_t)B_ * N_ * CODE_;
  float* Tmp   = ws + o; o += (size_t)B_ * N_ * HID_;
  float* hnX   = ws + o; o += (size_t)B_ * N_ * HID_;
  float* Gbuf  = ws + o; o += (size_t)4 * GID_ * HID_;
  const size_t hn_bytes = (size_t)B_ * N_ * HID_ * sizeof(float);

  const dim3 blk(256);
  float* logits = (float*)d_out;
  float* fmap   = (float*)d_out + (size_t)B_ * N_ * FEAT_;

  // encoder fc1
  gemm_bias<1><<<dim3(6, 12), blk, 0, stream>>>(features, EMB_, enc_fc1_W, enc_fc1_b,
                                                Hse, CONC_, EMB_);
  // encoder scans
  for (int l = 0; l < 2; ++l) {
    const float* Hl = Hse + l * HID_;
    gemm_bias<0><<<dim3(18, 12), blk, 0, stream>>>(Hl, CONC_,
        enc_gruc_Wih + (size_t)l * GID_ * HID_, enc_gruc_bih + l * GID_, GIc, GID_, HID_);
    gemm_bias<0><<<dim3(18, 12), blk, 0, stream>>>(Hl, CONC_,
        enc_grup_Whh + (size_t)l * GID_ * HID_, enc_grup_bhh + l * GID_, GHp, GID_, HID_);
    prod_kernel<<<dim3(6, 18, 4), blk, 0, stream>>>(
        enc_gruc_Whh + (size_t)l * GID_ * HID_, enc_grup_Wih + (size_t)l * GID_ * HID_,
        enc_Wr0 + (size_t)l * HID_ * HID_, enc_Wr1 + (size_t)l * HID_ * HID_, Gbuf);
    hipMemsetAsync(hnX, 0xFF, hn_bytes, stream);
    ScanP p;
    p.Hl = Hl; p.bufC = Hse + (l + 1) * HID_;
    p.hnX = hnX; p.G = Gbuf;
    p.GIc = GIc; p.GHp = GHp;
    p.bhhc = enc_gruc_bhh + l * GID_;
    p.bihp = enc_grup_bih + l * GID_;
    p.Wr0 = enc_Wr0 + (size_t)l * HID_ * HID_;
    p.Wr1 = enc_Wr1 + (size_t)l * HID_ * HID_;
    p.wk = enc_gat_w + l * 2 * HID_ + HID_;
    p.mask = adj; p.smask = s_mask;
    p.adjB = (l == 0) ? adjB1 : adjB2;
    scan_kernel<1><<<dim3(512), blk, 0, stream>>>(p);
  }
  // encoder MLP -> fU
  gemm_bias<1><<<dim3(6, 12), blk, 0, stream>>>(Hse, CONC_, enc_mlp_W0, enc_mlp_b0,
                                                Tmp, HID_, CONC_);
  gemm_bias<0><<<dim3(3, 12), blk, 0, stream>>>(Tmp, HID_, enc_mlp_W1, enc_mlp_b1,
                                                fU, CODE_, HID_);
  // decoder fc1
  gemm_bias<1><<<dim3(6, 12), blk, 0, stream>>>(fU, CODE_, dec_fc1_W, dec_fc1_b,
                                                Hsd, CONC_, CODE_);
  // decoder scans
  for (int l = 0; l < 2; ++l) {
    const float* Hl = Hsd + l * HID_;
    gemm_bias<0><<<dim3(18, 12), blk, 0, stream>>>(Hl, CONC_,
        dec_gruc_Wih + (size_t)l * GID_ * HID_, dec_gruc_bih + l * GID_, GIc, GID_, HID_);
    gemm_bias<0><<<dim3(18, 12), blk, 0, stream>>>(Hl, CONC_,
        dec_grup_Whh + (size_t)l * GID_ * HID_, dec_grup_bhh + l * GID_, GHp, GID_, HID_);
    prod_kernel<<<dim3(6, 18, 4), blk, 0, stream>>>(
        dec_gruc_Whh + (size_t)l * GID_ * HID_, dec_grup_Wih + (size_t)l * GID_ * HID_,
        dec_Wr0 + (size_t)l * HID_ * HID_, dec_Wr1 + (size_t)l * HID_ * HID_, Gbuf);
    hipMemsetAsync(hnX, 0xFF, hn_bytes, stream);
    ScanP p;
    p.Hl = Hl; p.bufC = Hsd + (l + 1) * HID_;
    p.hnX = hnX; p.G = Gbuf;
    p.GIc = GIc; p.GHp = GHp;
    p.bhhc = dec_gruc_bhh + l * GID_;
    p.bihp = dec_grup_bih + l * GID_;
    p.Wr0 = dec_Wr0 + (size_t)l * HID_ * HID_;
    p.Wr1 = dec_Wr1 + (size_t)l * HID_ * HID_;
    p.wk = nullptr;
    p.mask = (l == 0) ? adjB1 : adjB2;   // w[n] = -adjB[b,i,n] for n<i
    p.smask = s_mask;
    p.adjB = nullptr;
    scan_kernel<0><<<dim3(512), blk, 0, stream>>>(p);
  }
  // decoder MLP -> logits
  gemm_bias<1><<<dim3(6, 12), blk, 0, stream>>>(Hsd, CONC_, dec_mlp_W0, dec_mlp_b0,
                                                Tmp, HID_, CONC_);
  gemm_bias<0><<<dim3(12, 12), blk, 0, stream>>>(Tmp, HID_, dec_mlp_W1, dec_mlp_b1,
                                                 logits, FEAT_, HID_);
  // feature_map
  fmap_kernel<<<dim3((B_ * N_ * N_ + 255) / 256), blk, 0, stream>>>(adjB2, fmap);
}

// Round 17
// 1899.340 us; speedup vs baseline: 1.4089x; 1.0316x over previous
//
#include <hip/hip_runtime.h>
#include <math.h>

#define B_    8
#define N_    96
#define EMB_  768
#define HID_  384
#define GID_  1152   // 3*HID
#define CONC_ 1152   // (L+1)*HID
#define CODE_ 192
#define FEAT_ 768
#define NSL_  64     // slices per batch
#define SD_   6      // dims per slice
#define NRW_  42     // 36 gate rows + 6 M rows (history rows per block)

__device__ __forceinline__ float sigf(float x) { return 1.0f / (1.0f + expf(-x)); }

// LLC-coherent (agent-scope) relaxed atomic accessors (proven visibility path).
__device__ __forceinline__ void atstf(float* p, float v) {
  __hip_atomic_store(p, v, __ATOMIC_RELAXED, __HIP_MEMORY_SCOPE_AGENT);
}
__device__ __forceinline__ float atldf(const float* p) {
  return __hip_atomic_load((float*)p, __ATOMIC_RELAXED, __HIP_MEMORY_SCOPE_AGENT);
}
__device__ __forceinline__ float dot4(float4 a, float4 b) {
  return fmaf(a.x, b.x, fmaf(a.y, b.y, fmaf(a.z, b.z, a.w * b.w)));
}

// ---------------- generic GEMM: C[M,N] = act(A @ W^T + bias) ----------------
template<int RELU>
__global__ __launch_bounds__(256)
void gemm_bias(const float* __restrict__ A, int lda,
               const float* __restrict__ W,
               const float* __restrict__ bias,
               float* __restrict__ C, int ldc, int K)
{
  __shared__ float As[16][68];
  __shared__ float Bs[16][68];
  const int tid = threadIdx.x;
  const int m0 = blockIdx.y * 64;
  const int n0 = blockIdx.x * 64;
  const int lr = tid >> 2;
  const int lc = (tid & 3) * 4;
  const int ty = tid >> 4, tx = tid & 15;
  float acc[4][4] = {};
  for (int k0 = 0; k0 < K; k0 += 16) {
    float4 a4 = *(const float4*)(A + (size_t)(m0 + lr) * lda + k0 + lc);
    float4 b4 = *(const float4*)(W + (size_t)(n0 + lr) * K + k0 + lc);
    As[lc+0][lr] = a4.x; As[lc+1][lr] = a4.y; As[lc+2][lr] = a4.z; As[lc+3][lr] = a4.w;
    Bs[lc+0][lr] = b4.x; Bs[lc+1][lr] = b4.y; Bs[lc+2][lr] = b4.z; Bs[lc+3][lr] = b4.w;
    __syncthreads();
#pragma unroll
    for (int k = 0; k < 16; ++k) {
      float av[4], bv[4];
#pragma unroll
      for (int i = 0; i < 4; ++i) av[i] = As[k][ty*4+i];
#pragma unroll
      for (int j = 0; j < 4; ++j) bv[j] = Bs[k][tx*4+j];
#pragma unroll
      for (int i = 0; i < 4; ++i)
#pragma unroll
        for (int j = 0; j < 4; ++j) acc[i][j] = fmaf(av[i], bv[j], acc[i][j]);
    }
    __syncthreads();
  }
#pragma unroll
  for (int i = 0; i < 4; ++i) {
    int m = m0 + ty*4 + i;
#pragma unroll
    for (int j = 0; j < 4; ++j) {
      int n = n0 + tx*4 + j;
      float v = acc[i][j] + bias[n];
      if (RELU) v = fmaxf(v, 0.0f);
      C[(size_t)m * ldc + n] = v;
    }
  }
}

// ---- paired GEMM: z=0 -> C0 = A@W0^T+b0 ; z=1 -> C1 = A@W1^T+b1 (K=HID) ----
__global__ __launch_bounds__(256)
void gemm_bias2(const float* __restrict__ A,
                const float* __restrict__ W0, const float* __restrict__ b0,
                float* __restrict__ C0,
                const float* __restrict__ W1, const float* __restrict__ b1,
                float* __restrict__ C1)
{
  const float* W    = (blockIdx.z == 0) ? W0 : W1;
  const float* bias = (blockIdx.z == 0) ? b0 : b1;
  float*       C    = (blockIdx.z == 0) ? C0 : C1;
  __shared__ float As[16][68];
  __shared__ float Bs[16][68];
  const int tid = threadIdx.x;
  const int m0 = blockIdx.y * 64;
  const int n0 = blockIdx.x * 64;
  const int lr = tid >> 2;
  const int lc = (tid & 3) * 4;
  const int ty = tid >> 4, tx = tid & 15;
  float acc[4][4] = {};
  for (int k0 = 0; k0 < HID_; k0 += 16) {
    float4 a4 = *(const float4*)(A + (size_t)(m0 + lr) * CONC_ + k0 + lc);
    float4 b4 = *(const float4*)(W + (size_t)(n0 + lr) * HID_ + k0 + lc);
    As[lc+0][lr] = a4.x; As[lc+1][lr] = a4.y; As[lc+2][lr] = a4.z; As[lc+3][lr] = a4.w;
    Bs[lc+0][lr] = b4.x; Bs[lc+1][lr] = b4.y; Bs[lc+2][lr] = b4.z; Bs[lc+3][lr] = b4.w;
    __syncthreads();
#pragma unroll
    for (int k = 0; k < 16; ++k) {
      float av[4], bv[4];
#pragma unroll
      for (int i = 0; i < 4; ++i) av[i] = As[k][ty*4+i];
#pragma unroll
      for (int j = 0; j < 4; ++j) bv[j] = Bs[k][tx*4+j];
#pragma unroll
      for (int i = 0; i < 4; ++i)
#pragma unroll
        for (int j = 0; j < 4; ++j) acc[i][j] = fmaf(av[i], bv[j], acc[i][j]);
    }
    __syncthreads();
  }
#pragma unroll
  for (int i = 0; i < 4; ++i) {
    int m = m0 + ty*4 + i;
#pragma unroll
    for (int j = 0; j < 4; ++j) {
      int n = n0 + tx*4 + j;
      C[(size_t)m * GID_ + n] = acc[i][j] + bias[n];
    }
  }
}

// ---------- product GEMMs: G[q] = A_q @ W_q, A:[1152,384], W:[384,384] ------
// q = blockIdx.z: 0:Whhc@Wr0 1:Whhc@Wr1 2:Wihp@Wr0 3:Wihp@Wr1
__global__ __launch_bounds__(256)
void prod_kernel(const float* __restrict__ Ac, const float* __restrict__ Ap,
                 const float* __restrict__ W0, const float* __restrict__ W1,
                 float* __restrict__ G)
{
  const float* A = (blockIdx.z < 2) ? Ac : Ap;
  const float* W = (blockIdx.z & 1) ? W1 : W0;
  float* C = G + (size_t)blockIdx.z * GID_ * HID_;
  __shared__ float As[16][68];
  __shared__ float Bs[16][68];
  const int tid = threadIdx.x;
  const int m0 = blockIdx.y * 64;
  const int n0 = blockIdx.x * 64;
  const int lr = tid >> 2;
  const int lc = (tid & 3) * 4;
  const int lr2 = tid & 63, kq = tid >> 6;
  const int ty = tid >> 4, tx = tid & 15;
  float acc[4][4] = {};
  for (int k0 = 0; k0 < HID_; k0 += 16) {
    float4 a4 = *(const float4*)(A + (size_t)(m0 + lr) * HID_ + k0 + lc);
    As[lc+0][lr] = a4.x; As[lc+1][lr] = a4.y; As[lc+2][lr] = a4.z; As[lc+3][lr] = a4.w;
#pragma unroll
    for (int u = 0; u < 4; ++u) {
      int kl = kq * 4 + u;
      Bs[kl][lr2] = W[(size_t)(k0 + kl) * HID_ + n0 + lr2];
    }
    __syncthreads();
#pragma unroll
    for (int k = 0; k < 16; ++k) {
      float av[4], bv[4];
#pragma unroll
      for (int i = 0; i < 4; ++i) av[i] = As[k][ty*4+i];
#pragma unroll
      for (int j = 0; j < 4; ++j) bv[j] = Bs[k][tx*4+j];
#pragma unroll
      for (int i = 0; i < 4; ++i)
#pragma unroll
        for (int j = 0; j < 4; ++j) acc[i][j] = fmaf(av[i], bv[j], acc[i][j]);
    }
    __syncthreads();
  }
#pragma unroll
  for (int i = 0; i < 4; ++i)
#pragma unroll
    for (int j = 0; j < 4; ++j)
      C[(size_t)(m0 + ty*4 + i) * HID_ + n0 + tx*4 + j] = acc[i][j];
}

// ---------------- DAG scan kernel ----------------
// grid = 512 blocks: batch = blockIdx>>6, slice = blockIdx&63 (6 dims each).
// ONE exchange per step (hn all-gather); gates+M via G-product rows and
// incremental per-block history PA/PB. Per-scan private hnX (no mid-stream
// re-poison). Softmax uses split red4a/red4b (3 barriers, not 4).
struct ScanP {
  const float* Hl;      // q rows, stride CONC_
  float*       bufC;    // cached output rows, stride CONC_
  float*       hnX;     // [8,96,384] exchange (sentinel-filled, atomics)
  const float* G;       // [4][1152,384] products for this scan
  const float* GIc;     // [768,1152] q@Wih_c^T + bih_c
  const float* GHp;     // [768,1152] q@Whh_p^T + bhh_p
  const float* bhhc;    // [1152]
  const float* bihp;    // [1152]
  const float* Wr0;     // [384,384]
  const float* Wr1;     // [384,384]
  const float* wk;      // [384] (enc only)
  const float* mask;    // enc: adj; dec: adjB (negated use)
  const float* smask;   // [8,96,96]
  float*       adjB;    // enc output
};

template<int ENC>
__global__ __launch_bounds__(256, 2)
void scan_kernel(ScanP p)
{
  const int tid  = threadIdx.x;
  const int b    = blockIdx.x >> 6;
  const int sl   = blockIdx.x & 63;
  const int j0   = sl * SD_;
  const int team = tid >> 4, lane = tid & 15;

  __shared__ __align__(16) float stage[HID_];
  __shared__ float ws0[N_], ws1[N_], s_sm[N_];
  __shared__ float alpha[N_];
  __shared__ float dots[48];
  __shared__ float red4a[4], red4b[4];
  __shared__ float sh_aknew;
  __shared__ float PA[NRW_ * 97];
  __shared__ float PB[NRW_ * 97];

  // zero history so the unguarded dot loop multiplies 0*0 beyond column i-1
  for (int k = tid; k < NRW_ * 97; k += 256) { PA[k] = 0.f; PB[k] = 0.f; }

  // ---- hoist the block's 48 virtual row-pairs into registers ----
  // r = team + 16u: r<36 gate rows (g=r/6: 0..2 c-side r/z/n, 3..5 p-side),
  // r in 36..41: M rows (Wr0/Wr1); r==42: wk (enc); r>42: dummy.
  float4 wAr[3][6], wBr[3][6];
#pragma unroll
  for (int u = 0; u < 3; ++u) {
    const int r = team + 16 * u;
    const float *Aptr, *Bptr;
    if (r < 36) {
      const int g = r / 6, jl = r % 6;
      const size_t off = (size_t)((g % 3) * HID_ + j0 + jl) * HID_;
      const float* base = p.G + (g < 3 ? 0 : 2) * (size_t)GID_ * HID_;
      Aptr = base + off;
      Bptr = base + (size_t)GID_ * HID_ + off;
    } else if (r < 42) {
      const int jl = r - 36;
      Aptr = p.Wr0 + (size_t)(j0 + jl) * HID_;
      Bptr = p.Wr1 + (size_t)(j0 + jl) * HID_;
    } else if (r == 42 && ENC) {
      Aptr = p.wk; Bptr = p.wk;
    } else {
      Aptr = p.Wr0; Bptr = p.Wr1;   // dummy rows, results unused
    }
#pragma unroll
    for (int m = 0; m < 6; ++m) {
      wAr[u][m] = ((const float4*)Aptr)[lane + 16*m];
      wBr[u][m] = ((const float4*)Bptr)[lane + 16*m];
    }
  }
  float bh0=0, bh1=0, bh2=0, bi0=0, bi1=0, bi2=0;
  if (tid < SD_) {
    int j = j0 + tid;
    bh0 = p.bhhc[j]; bh1 = p.bhhc[HID_ + j]; bh2 = p.bhhc[2*HID_ + j];
    bi0 = p.bihp[j]; bi1 = p.bihp[HID_ + j]; bi2 = p.bihp[2*HID_ + j];
  }

#define BULK_STAGE(SRC)                                                      \
  do {                                                                       \
    if (tid < NSL_) {                                                        \
      const float* f_ = (SRC) + tid * SD_;                                   \
      while (__float_as_uint(atldf(f_)) == 0xFFFFFFFFu) {}                   \
    }                                                                        \
    __syncthreads();                                                         \
    {                                                                        \
      float v0 = atldf((SRC) + tid);                                         \
      while (__float_as_uint(v0) == 0xFFFFFFFFu) v0 = atldf((SRC) + tid);    \
      stage[tid] = v0;                                                       \
      if (tid < HID_ - 256) {                                                \
        float v1 = atldf((SRC) + 256 + tid);                                 \
        while (__float_as_uint(v1) == 0xFFFFFFFFu)                           \
          v1 = atldf((SRC) + 256 + tid);                                     \
        stage[256 + tid] = v1;                                               \
      }                                                                      \
    }                                                                        \
    __syncthreads();                                                         \
  } while (0)

  // ---- node 0 ----
  if (tid < SD_) {
    int j = j0 + tid;
    const float* gi = p.GIc + (size_t)(b * N_) * GID_;
    const float* gh = p.GHp + (size_t)(b * N_) * GID_;
    float rc = sigf(gi[j] + bh0);
    float zc = sigf(gi[HID_ + j] + bh1);
    float nc = tanhf(gi[2*HID_ + j] + rc * bh2);
    float outc = (1.0f - zc) * nc;
    float rp = sigf(bi0 + gh[j]);
    float zp = sigf(bi1 + gh[HID_ + j]);
    float np = tanhf(bi2 + rp * gh[2*HID_ + j]);
    float x0 = p.Hl[(size_t)(b * N_) * CONC_ + j];
    float h0 = outc + (1.0f - zp) * np + zp * x0;
    p.bufC[(size_t)(b * N_) * CONC_ + j] = h0;
    atstf(&p.hnX[(size_t)(b * N_) * HID_ + j], h0);
  }
  __syncthreads();

  for (int i = 1; i < N_; ++i) {
    // ---- prefetch step-i operands (hide under hn flight) ----
    float pf_gi0=0, pf_gi1=0, pf_gi2=0, pf_gh0=0, pf_gh1=0, pf_gh2=0, pf_q=0;
    if (tid < SD_) {
      int j = j0 + tid;
      const float* gi = p.GIc + ((size_t)b * N_ + i) * GID_;
      const float* gh = p.GHp + ((size_t)b * N_ + i) * GID_;
      pf_gi0 = gi[j]; pf_gi1 = gi[HID_ + j]; pf_gi2 = gi[2*HID_ + j];
      pf_gh0 = gh[j]; pf_gh1 = gh[HID_ + j]; pf_gh2 = gh[2*HID_ + j];
      pf_q   = p.Hl[((size_t)b * N_ + i) * CONC_ + j];
    }
    float pf_mrow = 0.0f;
    if (tid < N_) {
      pf_mrow = p.mask[((size_t)b * N_ + i) * N_ + tid];
      s_sm[tid] = p.smask[((size_t)b * N_ + i) * N_ + tid];
    }

    // ---- ONE exchange: wait + stage hn[i-1] ----
    const float* srcH = p.hnX + (size_t)(b * N_ + (i - 1)) * HID_;
    BULK_STAGE(srcH);
    const float4* st4 = (const float4*)stage;
    float4 hreg[6];
#pragma unroll
    for (int m = 0; m < 6; ++m) hreg[m] = st4[lane + 16*m];

    // ---- append history column: PA/PB[r][i-1] = A_r@h, B_r@h ----
#pragma unroll
    for (int u = 0; u < 3; ++u) {
      const int r = team + 16 * u;
      float a = 0.f, bv = 0.f;
#pragma unroll
      for (int m = 0; m < 6; ++m) {
        a  += dot4(wAr[u][m], hreg[m]);
        bv += dot4(wBr[u][m], hreg[m]);
      }
#pragma unroll
      for (int mm = 8; mm; mm >>= 1) {
        a  += __shfl_xor(a, mm);
        bv += __shfl_xor(bv, mm);
      }
      if (lane == 0) {
        if (r < NRW_) { PA[r * 97 + (i - 1)] = a; PB[r * 97 + (i - 1)] = bv; }
        else if (ENC && r == 42) sh_aknew = a;
      }
    }
    __syncthreads();

    // ---- attention weights, pre-scaled by s (3-barrier softmax) ----
    if (ENC) {
      if (tid == 0) alpha[i - 1] = sh_aknew;
      float av = -3.0e38f;
      if (tid < i) {
        float ak = (tid == i - 1) ? sh_aknew : alpha[tid];
        av = ak - (1.0f - pf_mrow) * 1e30f;
      }
      float v = av;
#pragma unroll
      for (int m = 32; m; m >>= 1) v = fmaxf(v, __shfl_xor(v, m));
      if ((tid & 63) == 0) red4a[tid >> 6] = v;
      __syncthreads();
      float mx = fmaxf(fmaxf(red4a[0], red4a[1]), fmaxf(red4a[2], red4a[3]));
      float e = (tid < i) ? expf(av - mx) : 0.0f;
      v = e;
#pragma unroll
      for (int m = 32; m; m >>= 1) v += __shfl_xor(v, m);
      if ((tid & 63) == 0) red4b[tid >> 6] = v;
      __syncthreads();
      float ssum = red4b[0] + red4b[1] + red4b[2] + red4b[3];
      if (tid < N_) {
        float w = (tid < i) ? e / ssum : 0.0f;
        float sv = s_sm[tid];
        ws0[tid] = w * sv;
        ws1[tid] = w - w * sv;
        if (sl == 0) p.adjB[((size_t)b * N_ + i) * N_ + tid] = w;
      }
      __syncthreads();
    } else {
      if (tid < N_) {
        float w = (tid < i) ? -pf_mrow : 0.0f;
        float sv = s_sm[tid];
        ws0[tid] = w * sv;
        ws1[tid] = w - w * sv;
      }
      __syncthreads();
    }

    // ---- dots[r] = sum_n ws0[n]*PA[r][n] + ws1[n]*PB[r][n] ----
    {
      float wsr0[6], wsr1[6];
#pragma unroll
      for (int k = 0; k < 6; ++k) {
        wsr0[k] = ws0[lane + 16*k];
        wsr1[k] = ws1[lane + 16*k];
      }
#pragma unroll
      for (int u = 0; u < 3; ++u) {
        const int r = team + 16 * u;
        if (r < NRW_) {
          float acc = 0.f;
#pragma unroll
          for (int k = 0; k < 6; ++k) {
            int n = lane + 16*k;
            acc = fmaf(wsr0[k], PA[r * 97 + n], fmaf(wsr1[k], PB[r * 97 + n], acc));
          }
#pragma unroll
          for (int mm = 8; mm; mm >>= 1) acc += __shfl_xor(acc, mm);
          if (lane == 0) dots[r] = acc;
        }
      }
    }
    __syncthreads();

    // ---- combine gates, publish hn ----
    if (tid < SD_) {
      int j = j0 + tid;
      float Mj = dots[36 + tid];
      float rc = sigf(pf_gi0 + dots[tid] + bh0);
      float zc = sigf(pf_gi1 + dots[6 + tid] + bh1);
      float nc = tanhf(pf_gi2 + rc * (dots[12 + tid] + bh2));
      float outc = (1.0f - zc) * nc + zc * Mj;
      float rp = sigf(dots[18 + tid] + bi0 + pf_gh0);
      float zp = sigf(dots[24 + tid] + bi1 + pf_gh1);
      float np = tanhf(dots[30 + tid] + bi2 + rp * pf_gh2);
      float hv = outc + (1.0f - zp) * np + zp * pf_q;
      p.bufC[((size_t)b * N_ + i) * CONC_ + j] = hv;
      atstf(&p.hnX[((size_t)b * N_ + i) * HID_ + j], hv);
    }
    __syncthreads();   // protect stage[]/dots before next iteration
  }
#undef BULK_STAGE
}

// ---------------- feature_map = I - adjB2 (row 0 implicit 0) ----------------
__global__ __launch_bounds__(256)
void fmap_kernel(const float* __restrict__ adjB2, float* __restrict__ out)
{
  int idx = blockIdx.x * 256 + threadIdx.x;
  if (idx < B_ * N_ * N_) {
    int j = idx % N_;
    int i = (idx / N_) % N_;
    float a = (i == 0) ? 0.0f : adjB2[idx];
    out[idx] = ((i == j) ? 1.0f : 0.0f) - a;
  }
}

// ---------------- orchestration ----------------
extern "C" void kernel_launch(void* const* d_in, const int* in_sizes, int n_in,
                              void* d_out, int out_size, void* d_ws, size_t ws_size,
                              hipStream_t stream)
{
  (void)in_sizes; (void)n_in; (void)out_size; (void)ws_size;
  const float* features     = (const float*)d_in[0];
  const float* adj          = (const float*)d_in[1];
  const float* s_mask       = (const float*)d_in[2];
  const float* enc_fc1_W    = (const float*)d_in[5];
  const float* enc_fc1_b    = (const float*)d_in[6];
  const float* enc_gat_w    = (const float*)d_in[7];
  const float* enc_Wr0      = (const float*)d_in[9];
  const float* enc_Wr1      = (const float*)d_in[10];
  const float* enc_gruc_Wih = (const float*)d_in[11];
  const float* enc_gruc_Whh = (const float*)d_in[12];
  const float* enc_gruc_bih = (const float*)d_in[13];
  const float* enc_gruc_bhh = (const float*)d_in[14];
  const float* enc_grup_Wih = (const float*)d_in[15];
  const float* enc_grup_Whh = (const float*)d_in[16];
  const float* enc_grup_bih = (const float*)d_in[17];
  const float* enc_grup_bhh = (const float*)d_in[18];
  const float* enc_mlp_W0   = (const float*)d_in[19];
  const float* enc_mlp_b0   = (const float*)d_in[20];
  const float* enc_mlp_W1   = (const float*)d_in[21];
  const float* enc_mlp_b1   = (const float*)d_in[22];
  const float* dec_fc1_W    = (const float*)d_in[23];
  const float* dec_fc1_b    = (const float*)d_in[24];
  const float* dec_Wr0      = (const float*)d_in[25];
  const float* dec_Wr1      = (const float*)d_in[26];
  const float* dec_gruc_Wih = (const float*)d_in[27];
  const float* dec_gruc_Whh = (const float*)d_in[28];
  const float* dec_gruc_bih = (const float*)d_in[29];
  const float* dec_gruc_bhh = (const float*)d_in[30];
  const float* dec_grup_Wih = (const float*)d_in[31];
  const float* dec_grup_Whh = (const float*)d_in[32];
  const float* dec_grup_bih = (const float*)d_in[33];
  const float* dec_grup_bhh = (const float*)d_in[34];
  const float* dec_mlp_W0   = (const float*)d_in[35];
  const float* dec_mlp_b0   = (const float*)d_in[36];
  const float* dec_mlp_W1   = (const float*)d_in[37];
  const float* dec_mlp_b1   = (const float*)d_in[38];

  float* ws = (float*)d_ws;
  size_t o = 0;
  float* Hse   = ws + o; o += (size_t)B_ * N_ * CONC_;
  float* Hsd   = ws + o; o += (size_t)B_ * N_ * CONC_;
  float* GIc   = ws + o; o += (size_t)B_ * N_ * GID_;
  float* GHp   = ws + o; o += (size_t)B_ * N_ * GID_;
  float* adjB1 = ws + o; o += (size_t)B_ * N_ * N_;
  float* adjB2 = ws + o; o += (size_t)B_ * N_ * N_;
  float* fU    = ws + o; o += (size_t)B_ * N_ * CODE_;
  float* Tmp   = ws + o; o += (size_t)B_ * N_ * HID_;
  float* hnX4  = ws + o; o += (size_t)4 * B_ * N_ * HID_;   // one per scan
  float* Gbuf  = ws + o; o += (size_t)4 * GID_ * HID_;
  const size_t hn_elems = (size_t)B_ * N_ * HID_;

  const dim3 blk(256);
  float* logits = (float*)d_out;
  float* fmap   = (float*)d_out + (size_t)B_ * N_ * FEAT_;

  // sentinel-fill ALL four per-scan exchange buffers once
  hipMemsetAsync(hnX4, 0xFF, 4 * hn_elems * sizeof(float), stream);

  // encoder fc1
  gemm_bias<1><<<dim3(6, 12), blk, 0, stream>>>(features, EMB_, enc_fc1_W, enc_fc1_b,
                                                Hse, CONC_, EMB_);
  // encoder scans
  for (int l = 0; l < 2; ++l) {
    const float* Hl = Hse + l * HID_;
    gemm_bias2<<<dim3(18, 12, 2), blk, 0, stream>>>(Hl,
        enc_gruc_Wih + (size_t)l * GID_ * HID_, enc_gruc_bih + l * GID_, GIc,
        enc_grup_Whh + (size_t)l * GID_ * HID_, enc_grup_bhh + l * GID_, GHp);
    prod_kernel<<<dim3(6, 18, 4), blk, 0, stream>>>(
        enc_gruc_Whh + (size_t)l * GID_ * HID_, enc_grup_Wih + (size_t)l * GID_ * HID_,
        enc_Wr0 + (size_t)l * HID_ * HID_, enc_Wr1 + (size_t)l * HID_ * HID_, Gbuf);
    ScanP p;
    p.Hl = Hl; p.bufC = Hse + (l + 1) * HID_;
    p.hnX = hnX4 + (size_t)l * hn_elems; p.G = Gbuf;
    p.GIc = GIc; p.GHp = GHp;
    p.bhhc = enc_gruc_bhh + l * GID_;
    p.bihp = enc_grup_bih + l * GID_;
    p.Wr0 = enc_Wr0 + (size_t)l * HID_ * HID_;
    p.Wr1 = enc_Wr1 + (size_t)l * HID_ * HID_;
    p.wk = enc_gat_w + l * 2 * HID_ + HID_;
    p.mask = adj; p.smask = s_mask;
    p.adjB = (l == 0) ? adjB1 : adjB2;
    scan_kernel<1><<<dim3(512), blk, 0, stream>>>(p);
  }
  // encoder MLP -> fU
  gemm_bias<1><<<dim3(6, 12), blk, 0, stream>>>(Hse, CONC_, enc_mlp_W0, enc_mlp_b0,
                                                Tmp, HID_, CONC_);
  gemm_bias<0><<<dim3(3, 12), blk, 0, stream>>>(Tmp, HID_, enc_mlp_W1, enc_mlp_b1,
                                                fU, CODE_, HID_);
  // decoder fc1
  gemm_bias<1><<<dim3(6, 12), blk, 0, stream>>>(fU, CODE_, dec_fc1_W, dec_fc1_b,
                                                Hsd, CONC_, CODE_);
  // decoder scans
  for (int l = 0; l < 2; ++l) {
    const float* Hl = Hsd + l * HID_;
    gemm_bias2<<<dim3(18, 12, 2), blk, 0, stream>>>(Hl,
        dec_gruc_Wih + (size_t)l * GID_ * HID_, dec_gruc_bih + l * GID_, GIc,
        dec_grup_Whh + (size_t)l * GID_ * HID_, dec_grup_bhh + l * GID_, GHp);
    prod_kernel<<<dim3(6, 18, 4), blk, 0, stream>>>(
        dec_gruc_Whh + (size_t)l * GID_ * HID_, dec_grup_Wih + (size_t)l * GID_ * HID_,
        dec_Wr0 + (size_t)l * HID_ * HID_, dec_Wr1 + (size_t)l * HID_ * HID_, Gbuf);
    ScanP p;
    p.Hl = Hl; p.bufC = Hsd + (l + 1) * HID_;
    p.hnX = hnX4 + (size_t)(2 + l) * hn_elems; p.G = Gbuf;
    p.GIc = GIc; p.GHp = GHp;
    p.bhhc = dec_gruc_bhh + l * GID_;
    p.bihp = dec_grup_bih + l * GID_;
    p.Wr0 = dec_Wr0 + (size_t)l * HID_ * HID_;
    p.Wr1 = dec_Wr1 + (size_t)l * HID_ * HID_;
    p.wk = nullptr;
    p.mask = (l == 0) ? adjB1 : adjB2;   // w[n] = -adjB[b,i,n] for n<i
    p.smask = s_mask;
    p.adjB = nullptr;
    scan_kernel<0><<<dim3(512), blk, 0, stream>>>(p);
  }
  // decoder MLP -> logits
  gemm_bias<1><<<dim3(6, 12), blk, 0, stream>>>(Hsd, CONC_, dec_mlp_W0, dec_mlp_b0,
                                                Tmp, HID_, CONC_);
  gemm_bias<0><<<dim3(12, 12), blk, 0, stream>>>(Tmp, HID_, dec_mlp_W1, dec_mlp_b1,
                                                 logits, FEAT_, HID_);
  // feature_map
  fmap_kernel<<<dim3((B_ * N_ * N_ + 255) / 256), blk, 0, stream>>>(adjB2, fmap);
}